// Round 5
// baseline (162.125 us; speedup 1.0000x reference)
//
#include <hip/hip_runtime.h>
#include <hip/hip_bf16.h>

#define NPIX (1 << 20)
#define HDIM 1024
#define FRAG_PER_IMG 131072
#define NB_FRAG 64
#define RBIT 0x40000000

// ============ global union-find with slot-encoded roots ============
// P[px] for masked px: parent pixel index (strictly smaller), or RBIT|slot
// if px is a component root. Parents only decrease -> acyclic; stale reads
// benign (extra hops, never wrong connectivity).
__device__ __forceinline__ int find_root_g(int* P, int x) {
    for (;;) {
        int v = P[x];
        if ((v & RBIT) || v == x) return x;
        int vp = P[v];
        if ((vp & RBIT) || vp == v) return v;
        P[x] = vp;   // path halving, benign race
        x = vp;
    }
}

__device__ __forceinline__ void unite_g(int* P, int a, int b) {
    int ra = find_root_g(P, a);
    int rb = find_root_g(P, b);
    while (ra != rb) {
        if (ra < rb) { int t = ra; ra = rb; rb = t; }   // ra = larger pixel
        int exp = P[ra];
        if ((exp & RBIT) || exp == ra) {
            int old = atomicCAS(&P[ra], exp, rb);
            if (old == exp) return;
        }
        ra = find_root_g(P, ra);
        rb = find_root_g(P, rb);
    }
}

// ============ LDS union-find over run nodes (id = row*16 + k) ============
__device__ __forceinline__ int find_r(int* R, int n) {
    int p = R[n];
    while (p != n) {
        int gp = R[p];
        if (gp == p) return p;
        R[n] = gp;   // compression, benign race
        n = gp;
        p = R[n];
    }
    return n;
}

__device__ __forceinline__ void unite_r(int* R, int a, int b) {
    a = find_r(R, a); b = find_r(R, b);
    while (a != b) {
        if (a < b) { int t = a; a = b; b = t; }
        int old = atomicCAS(&R[a], a, b);
        if (old == a) return;
        a = find_r(R, old); b = find_r(R, b);
    }
}

// ============ phase A: one 32x32 tile per WAVE (64-thread block) ============
// lane l: row r=l>>1, half h=l&1 (16 px = 4 float4). Single-wave block makes
// every __syncthreads near-free and puts ~16 independent tiles in flight/CU.
__global__ __launch_bounds__(64) void local_k(
        const float4* __restrict__ pred4, const float4* __restrict__ targ4,
        int* __restrict__ P, unsigned* __restrict__ mbits,
        int* __restrict__ fragRoot, float2* __restrict__ fragSums,
        int* __restrict__ fragCnt, int fragCap) {
    int tile = blockIdx.x;
    int img = tile >> 10;
    int ty = (tile >> 5) & 31, tx = tile & 31;
    int l = threadIdx.x;
    int r = l >> 1, h = l & 1;

    __shared__ int s_ruf[512];
    __shared__ float s_sum[1024];          // per-run (inter,union) pairs
    __shared__ int s_slot[512];
    __shared__ unsigned char s_rx[512];    // run xstart

    int rowg = img * HDIM + ty * 32 + r;
    int qb = rowg * 256 + tx * 8 + h * 4;

    float sv[16], iv[16];
    unsigned hm = 0;
    #pragma unroll
    for (int q = 0; q < 4; ++q) {
        float4 P4 = pred4[qb + q];
        float4 T4 = targ4[qb + q];
        float ss0 = P4.x + T4.x, ss1 = P4.y + T4.y, ss2 = P4.z + T4.z, ss3 = P4.w + T4.w;
        sv[q*4+0] = ss0; sv[q*4+1] = ss1; sv[q*4+2] = ss2; sv[q*4+3] = ss3;
        iv[q*4+0] = P4.x * T4.x; iv[q*4+1] = P4.y * T4.y;
        iv[q*4+2] = P4.z * T4.z; iv[q*4+3] = P4.w * T4.w;
        if (ss0 > 0.f) hm |= 1u << (q*4+0);
        if (ss1 > 0.f) hm |= 1u << (q*4+1);
        if (ss2 > 0.f) hm |= 1u << (q*4+2);
        if (ss3 > 0.f) hm |= 1u << (q*4+3);
    }
    unsigned m = hm << (h * 16);
    m |= __shfl_xor(m, 1);                 // full 32-bit row mask on both lanes

    if (__ballot(m != 0) == 0ull) {        // empty tile: mbits=0 and done
        if (h == 0) mbits[rowg * 32 + tx] = 0u;
        return;
    }

    #pragma unroll
    for (int k = 0; k < 8; ++k) s_ruf[l * 8 + k] = l * 8 + k;

    unsigned st = m & ~(m << 1);           // full-row run starts

    if (h == 0) {                          // run xstart table
        unsigned s2 = st; int k = 0;
        while (s2) { s_rx[r * 16 + k] = (unsigned char)(__ffs(s2) - 1); s2 &= s2 - 1; ++k; }
    }

    // ---- P3a: per-run sums, exclusive plain stores ----
    bool strad = (h == 1) && ((m >> 15) & 1) && ((m >> 16) & 1);
    int ridS = strad ? (__popc(st & 0x1FFFFu) - 1) : -2;
    float fi = 0.f, fu = 0.f;
    {
        int cur = -1; float ai = 0.f, au = 0.f;
        #pragma unroll
        for (int j = 0; j < 16; ++j) {
            if ((hm >> j) & 1) {
                int x = h * 16 + j;
                int rid = __popc(st & ((2u << x) - 1)) - 1;
                if (rid != cur) {
                    if (cur >= 0) {
                        if (cur == ridS) { fi = ai; fu = au; }
                        else { s_sum[(r*16+cur)*2] = ai; s_sum[(r*16+cur)*2+1] = au; }
                    }
                    cur = rid; ai = 0.f; au = 0.f;
                }
                ai += iv[j]; au += sv[j];
            }
        }
        if (cur >= 0) {
            if (cur == ridS) { fi = ai; fu = au; }
            else { s_sum[(r*16+cur)*2] = ai; s_sum[(r*16+cur)*2+1] = au; }
        }
    }
    __syncthreads();

    // ---- P3b: fold straddler partial (exclusive RMW now) ----
    if (strad) {
        s_sum[(r*16+ridS)*2]   += fi;
        s_sum[(r*16+ridS)*2+1] += fu;
    }
    // ---- P4: vertical run unions (lane pair per row boundary) ----
    {
        int bsrc = (l & ~1) + 2; if (bsrc > 63) bsrc = 63;
        unsigned ma = __shfl(m, l & ~1);
        unsigned mb = __shfl(m, bsrc);
        if (l < 62) {
            int rr = l >> 1;
            unsigned sta = ma & ~(ma << 1);
            unsigned stb = mb & ~(mb << 1);
            unsigned o = ma & mb;
            unsigned os = o & ~(o << 1);
            os &= h ? 0xFFFF0000u : 0x0000FFFFu;
            while (os) {
                int x = __ffs(os) - 1; os &= os - 1;
                unsigned below = (2u << x) - 1;
                unite_r(s_ruf, rr * 16 + __popc(sta & below) - 1,
                               (rr + 1) * 16 + __popc(stb & below) - 1);
            }
        }
    }
    __syncthreads();

    // ---- P5: flatten to depth<=1 + fold run sums into roots ----
    #pragma unroll
    for (int k = 0; k < 8; ++k) {
        int n = l * 8 + k;
        unsigned strow = __shfl(st, (n >> 4) * 2);
        if ((n & 15) < __popc(strow)) {
            int root = find_r(s_ruf, n);
            if (root != n) {
                s_ruf[n] = root;
                atomicAdd(&s_sum[root * 2],     s_sum[n * 2]);
                atomicAdd(&s_sum[root * 2 + 1], s_sum[n * 2 + 1]);
            }
        }
    }
    __syncthreads();

    // ---- P7: enumerate root runs -> fragment slots (1 global atomic/wave) ----
    int mycnt = 0;
    bool isroot[8];
    #pragma unroll
    for (int k = 0; k < 8; ++k) {
        int n = l * 8 + k;
        unsigned strow = __shfl(st, (n >> 4) * 2);
        bool rt = ((n & 15) < __popc(strow)) && (s_ruf[n] == n);
        isroot[k] = rt;
        mycnt += rt;
    }
    int inc = mycnt;
    #pragma unroll
    for (int d = 1; d < 64; d <<= 1) {
        int tsh = __shfl_up(inc, d);
        if (l >= d) inc += tsh;
    }
    int total = __shfl(inc, 63);
    int base = 0;
    if (l == 63 && total > 0) base = atomicAdd(fragCnt, total);
    base = __shfl(base, 63);
    int o = base + inc - mycnt;
    #pragma unroll
    for (int k = 0; k < 8; ++k) {
        if (isroot[k]) {
            int n = l * 8 + k;
            int slot = o++;
            if (slot < fragCap) {
                int rr2 = n >> 4;
                int gr = (img * HDIM + ty * 32 + rr2) * HDIM + tx * 32 + (int)s_rx[n];
                fragRoot[slot] = gr;
                fragSums[slot] = make_float2(s_sum[n * 2], s_sum[n * 2 + 1]);
                s_slot[n] = slot;
            } else s_slot[n] = 0;
        }
    }
    __syncthreads();

    // ---- P6: per-pixel parent quads (root pixel gets RBIT|slot inline) ----
    int pbase = rowg * HDIM + tx * 32 + h * 16;
    int rcur = -1, curGr = 0, curRR = -1, curXR = -1, curTag = 0;
    #pragma unroll
    for (int q = 0; q < 4; ++q) {
        int pv[4];
        unsigned qm = (hm >> (q * 4)) & 0xFu;
        #pragma unroll
        for (int j = 0; j < 4; ++j) {
            int jj = q * 4 + j;
            int x = h * 16 + jj;
            pv[j] = 0;
            if ((hm >> jj) & 1) {
                int rid = __popc(st & ((2u << x) - 1)) - 1;
                if (rid != rcur) {
                    rcur = rid;
                    int root = s_ruf[r * 16 + rid];
                    curRR = root >> 4;
                    curXR = (int)s_rx[root];
                    curGr = (img * HDIM + ty * 32 + curRR) * HDIM + tx * 32 + curXR;
                    curTag = RBIT | s_slot[root];
                }
                pv[j] = (curRR == r && curXR == x) ? curTag : curGr;
            }
        }
        if (qm) *(int4*)(P + pbase + q * 4) = make_int4(pv[0], pv[1], pv[2], pv[3]);
    }
    if (h == 0) mbits[rowg * 32 + tx] = m;
}

// ============ phase B: boundary unions (63488 edges/image) ============
__global__ void bound_k(const unsigned* __restrict__ mbits, int* __restrict__ P) {
    int img = blockIdx.x / 248;
    int e = (blockIdx.x % 248) * 256 + threadIdx.x;
    int g1, g2;
    if (e < 31744) {            // vertical boundary: x = 32k+31 <-> x+1
        int k = e >> 10, y = e & 1023;
        unsigned w1 = mbits[(img * HDIM + y) * 32 + k];
        unsigned w2 = mbits[(img * HDIM + y) * 32 + k + 1];
        if (!(w1 >> 31) || !(w2 & 1)) return;
        g1 = img * NPIX + y * HDIM + k * 32 + 31;
        g2 = g1 + 1;
    } else {                    // horizontal boundary: y = 32k+31 <-> y+1
        int e2 = e - 31744;
        int k = e2 >> 10, x = e2 & 1023;
        int y = k * 32 + 31;
        unsigned w1 = mbits[(img * HDIM + y) * 32 + (x >> 5)];
        unsigned w2 = mbits[(img * HDIM + y + 1) * 32 + (x >> 5)];
        unsigned b = x & 31;
        if (!((w1 >> b) & 1) || !((w2 >> b) & 1)) return;
        g1 = img * NPIX + y * HDIM + x;
        g2 = g1 + HDIM;
    }
    unite_g(P, g1, g2);
}

// ============ phase C: fold donor fragments into final roots ============
__global__ void merge_frag_k(const int* __restrict__ fragRoot, const int* __restrict__ fragCnt,
                             int* __restrict__ P, float* __restrict__ fragSums, int fragCap) {
    int n = fragCnt[0]; if (n > fragCap) n = fragCap;
    for (int i = blockIdx.x * blockDim.x + threadIdx.x; i < n;
         i += gridDim.x * blockDim.x) {
        int r0 = fragRoot[i];
        int r = find_root_g(P, r0);
        if (r != r0) {
            int v = P[r];
            if (v & RBIT) {
                int s = v & (RBIT - 1);
                float2 d = ((const float2*)fragSums)[i];
                unsafeAtomicAdd(&fragSums[2 * s], d.x);
                unsafeAtomicAdd(&fragSums[2 * s + 1], d.y);
            }
        }
    }
}

// ============ phase D: dice over final roots, block partials ============
__global__ void dice_frag_k(const int* __restrict__ fragRoot, const int* __restrict__ fragCnt,
                            const int* __restrict__ P, const float2* __restrict__ fragSums,
                            float* __restrict__ partials, int b0, int B, int fragCap) {
    __shared__ float sb[8][2];
    if (threadIdx.x < 16) ((float*)sb)[threadIdx.x] = 0.f;
    __syncthreads();
    int n = fragCnt[0]; if (n > fragCap) n = fragCap;
    for (int i = blockIdx.x * blockDim.x + threadIdx.x; i < n;
         i += gridDim.x * blockDim.x) {
        int r0 = fragRoot[i];
        if (!(P[r0] & RBIT)) continue;   // not a final root
        float2 su = fragSums[i];
        float d = (2.f * su.x + 1e-6f) / (su.y + 1e-6f);
        int ci = r0 >> 20;               // chunk-local image
        atomicAdd(&sb[ci][0], d);
        atomicAdd(&sb[ci][1], 1.f);
    }
    __syncthreads();
    if (threadIdx.x < 16) {
        int ci = threadIdx.x >> 1, j = threadIdx.x & 1;
        int imgg = b0 + ci;
        if (imgg < B)
            partials[(blockIdx.x * B + imgg) * 2 + j] += ((float*)sb)[threadIdx.x];
    }
}

__global__ void zero_partials_k(float* __restrict__ p, int n, int* __restrict__ fragCnt) {
    int i = blockIdx.x * blockDim.x + threadIdx.x;
    if (i < n) p[i] = 0.f;
    if (i == 0) fragCnt[0] = 0;
}
__global__ void zero_frag_k(int* __restrict__ fragCnt) {
    if (threadIdx.x == 0) fragCnt[0] = 0;
}

__global__ void final_k(const float* __restrict__ partials, float* __restrict__ out, int B) {
    __shared__ float sb[128][2];
    int t = threadIdx.x;
    if (t < 2 * B) {
        int img = t >> 1, j = t & 1;
        float a = 0.f;
        for (int bkt = 0; bkt < NB_FRAG; ++bkt) a += partials[(bkt * B + img) * 2 + j];
        sb[img][j] = a;
    }
    __syncthreads();
    if (t == 0) {
        float acc = 0.f;
        for (int img = 0; img < B; ++img) {
            float s = sb[img][0], nn = sb[img][1];
            acc += (nn > 0.f) ? (1.f - s / nn) : 1.f;
        }
        out[0] = acc / (float)B;
    }
}

// ============ launch ============
extern "C" void kernel_launch(void* const* d_in, const int* in_sizes, int n_in,
                              void* d_out, int out_size, void* d_ws, size_t ws_size,
                              hipStream_t stream) {
    const float* pred = (const float*)d_in[0];
    const float* targ = (const float*)d_in[1];
    float* out = (float*)d_out;
    int B = in_sizes[0] / NPIX;
    if (B < 1) B = 1;

    char* ws = (char*)d_ws;
    size_t off = 0;
    float* partials = (float*)ws;
    off += ((size_t)NB_FRAG * B * 2 * sizeof(float) + 255) & ~(size_t)255;
    int* fragCnt = (int*)(ws + off);
    off += 256;
    size_t fixed = off;

    const size_t perImg = (size_t)NPIX * 4 + (size_t)HDIM * 32 * 4
                        + (size_t)FRAG_PER_IMG * 4 + (size_t)FRAG_PER_IMG * 8;
    int maxC = 1;
    if (ws_size > fixed + perImg) {
        size_t m = (ws_size - fixed) / perImg;
        maxC = (int)(m < (size_t)B ? m : (size_t)B);
        if (maxC < 1) maxC = 1;
        if (maxC > 8) maxC = 8;
    }
    int*      P        = (int*)     (ws + off); off += (size_t)maxC * NPIX * 4;
    unsigned* mbits    = (unsigned*)(ws + off); off += (size_t)maxC * HDIM * 32 * 4;
    int*      fragRoot = (int*)     (ws + off); off += (size_t)maxC * FRAG_PER_IMG * 4;
    float2*   fragSums = (float2*)  (ws + off);

    zero_partials_k<<<(NB_FRAG * B * 2 + 255) / 256, 256, 0, stream>>>(
        partials, NB_FRAG * B * 2, fragCnt);

    for (int b0 = 0; b0 < B; b0 += maxC) {
        int C = (B - b0 < maxC) ? (B - b0) : maxC;
        const float* pc = pred + (size_t)b0 * NPIX;
        const float* tc = targ + (size_t)b0 * NPIX;
        int fragCap = C * FRAG_PER_IMG;
        if (b0 > 0) zero_frag_k<<<1, 64, 0, stream>>>(fragCnt);
        local_k<<<C * 1024, 64, 0, stream>>>((const float4*)pc, (const float4*)tc,
                                             P, mbits, fragRoot, fragSums, fragCnt, fragCap);
        bound_k<<<C * 248, 256, 0, stream>>>(mbits, P);
        merge_frag_k<<<128, 256, 0, stream>>>(fragRoot, fragCnt, P, (float*)fragSums, fragCap);
        dice_frag_k<<<NB_FRAG, 256, 0, stream>>>(fragRoot, fragCnt, P, fragSums,
                                                 partials, b0, B, fragCap);
    }

    final_k<<<1, 256, 0, stream>>>(partials, out, B);
}